// Round 5
// baseline (365.606 us; speedup 1.0000x reference)
//
#include <hip/hip_runtime.h>

// B=128, S=1024, H=256
#define Bb 128
#define Ss 1024
#define Hh 256
#define NEGF 1e9f

typedef short bf16x8 __attribute__((ext_vector_type(8)));
typedef float f32x4 __attribute__((ext_vector_type(4)));

__device__ __forceinline__ short f2bf(float f) {
    union { float f; unsigned u; } c; c.f = f;
    return (short)((c.u + 0x8000u) >> 16);
}

__device__ __forceinline__ unsigned pack2bf(float lo, float hi) {
    union { float f; unsigned u; } a, b; a.f = lo; b.f = hi;
    return ((a.u + 0x8000u) >> 16) | ((b.u + 0x8000u) & 0xFFFF0000u);
}

__device__ __forceinline__ float bfhi2f(unsigned u) {
    union { unsigned u; float f; } c; c.u = u & 0xFFFF0000u; return c.f;
}
__device__ __forceinline__ float bflo2f(unsigned u) {
    union { unsigned u; float f; } c; c.u = u << 16; return c.f;
}

__device__ __forceinline__ float fast_tanh(float x) {
    float cl = fminf(fmaxf(x, -10.f), 10.f);
    float e = __expf(2.f * cl);
    return (e - 1.f) * __builtin_amdgcn_rcpf(e + 1.f);
}

// ---------------- convert wg, wp (fp32 [H,H]) -> bf16 --------------------------
__global__ __launch_bounds__(256) void convert_w(const float* __restrict__ wg,
                                                 const float* __restrict__ wp,
                                                 short* __restrict__ wgb,
                                                 short* __restrict__ wpb) {
    int i = blockIdx.x * 256 + threadIdx.x;
    wgb[i] = f2bf(wg[i]);
    wpb[i] = f2bf(wp[i]);
}

// ---------------- small GEMV: out[b,h] = sum_d q[b,d]*W[h,d] + bias[h] ----------
__global__ __launch_bounds__(256) void dot_qb(const float* __restrict__ q,
                                              const float* __restrict__ W,
                                              const float* __restrict__ bias,
                                              float* __restrict__ out) {
    int b = blockIdx.x, h = threadIdx.x;
    const float4* qr = (const float4*)(q + b * Hh);
    const float4* wr = (const float4*)(W + h * Hh);
    float acc = 0.f;
#pragma unroll 8
    for (int i = 0; i < Hh / 4; ++i) {
        float4 q4 = qr[i], w4 = wr[i];
        acc += q4.x * w4.x + q4.y * w4.y + q4.z * w4.z + q4.w * w4.w;
    }
    out[b * Hh + h] = acc + bias[h];
}

// ---------------- scores[b,s] = sum_n tanh((ref@W^T)[s,n] + qbias[b,n]) * v[n]
// Block: 32 s-rows x all 256 n. 4 waves, each wave owns a 64-n strip.
// A tile staged once via LDS (padded rows, 2-way-free bank aliasing); A-frags in
// registers; B-frags loaded per n-subtile straight from L2 into registers.
// No barriers in the compute loop. Optionally converts fp32 ref -> bf16 side out.
template <int MASKED, int LOADF32>
__global__ __launch_bounds__(256, 2) void scores_v5(const float* __restrict__ reff,
                                                    const unsigned* __restrict__ refb_in,
                                                    unsigned* __restrict__ refb_out,
                                                    const short* __restrict__ Wbf,
                                                    const float* __restrict__ qbias,
                                                    const float* __restrict__ vvec,
                                                    const int* __restrict__ mask,
                                                    float* __restrict__ out) {
    __shared__ short A[32 * 264];     // 32 rows x 256 bf16, rows padded +8 shorts
    __shared__ float part[4][32];
    const int b = blockIdx.x;
    const int s0 = blockIdx.y * 32;
    const int t = threadIdx.x;
    const int wave = t >> 6, lane = t & 63, nl = lane & 15, quad = lane >> 4;

    if (LOADF32) {
        // stage fp32 tile -> LDS bf16 (+ write bf16 ref side-output, coalesced)
        const float4* src = (const float4*)(reff + ((size_t)b * Ss + s0) * Hh);
        unsigned* dst = refb_out + ((size_t)b * Ss + s0) * (Hh / 2);
#pragma unroll
        for (int i = 0; i < 8; ++i) {
            int f4 = i * 256 + t;             // float4 index; 64 per row
            float4 v = src[f4];
            unsigned lo = pack2bf(v.x, v.y), hi = pack2bf(v.z, v.w);
            int row = f4 >> 6, col4 = f4 & 63;
            *(uint2*)&A[row * 264 + col4 * 4] = make_uint2(lo, hi);
            *(uint2*)&dst[(size_t)f4 * 2] = make_uint2(lo, hi);
        }
    } else {
        const uint4* src = (const uint4*)(refb_in + ((size_t)b * Ss + s0) * (Hh / 2));
#pragma unroll
        for (int i = 0; i < 4; ++i) {
            int u4 = i * 256 + t;             // uint4 index; 32 per row
            uint4 v = src[u4];
            int row = u4 >> 5, c = u4 & 31;
            *(uint4*)&A[row * 264 + c * 8] = v;
        }
    }
    __syncthreads();

    // A fragments: A[m = rt*16+nl][k = kb*32 + quad*8 + j]
    bf16x8 af[2][8];
#pragma unroll
    for (int rt = 0; rt < 2; ++rt)
#pragma unroll
        for (int kb = 0; kb < 8; ++kb)
            af[rt][kb] = *(const bf16x8*)&A[(rt * 16 + nl) * 264 + kb * 32 + quad * 8];

    // hoist qbias / v for this wave's 4 n-subtiles
    float qb[4], vv[4];
#pragma unroll
    for (int j = 0; j < 4; ++j) {
        int n = wave * 64 + j * 16 + nl;
        qb[j] = qbias[b * Hh + n];
        vv[j] = vvec[n];
    }

    float sc[2][4] = {{0.f, 0.f, 0.f, 0.f}, {0.f, 0.f, 0.f, 0.f}};
#pragma unroll
    for (int j = 0; j < 4; ++j) {
        const short* wr = Wbf + (wave * 64 + j * 16 + nl) * Hh;
        bf16x8 bf[8];
#pragma unroll
        for (int kb = 0; kb < 8; ++kb)
            bf[kb] = *(const bf16x8*)(wr + kb * 32 + quad * 8);
#pragma unroll
        for (int rt = 0; rt < 2; ++rt) {
            f32x4 c = {0.f, 0.f, 0.f, 0.f};
#pragma unroll
            for (int kb = 0; kb < 8; ++kb)
                c = __builtin_amdgcn_mfma_f32_16x16x32_bf16(af[rt][kb], bf[kb], c, 0, 0, 0);
            // C/D: col = lane&15 (= n-lane), row = quad*4 + r
#pragma unroll
            for (int r = 0; r < 4; ++r)
                sc[rt][r] += fast_tanh(c[r] + qb[j]) * vv[j];
        }
    }

    // reduce over the 16 n-lanes within each quad
#pragma unroll
    for (int rt = 0; rt < 2; ++rt)
#pragma unroll
        for (int r = 0; r < 4; ++r) {
            float v = sc[rt][r];
            v += __shfl_xor(v, 1, 64);
            v += __shfl_xor(v, 2, 64);
            v += __shfl_xor(v, 4, 64);
            v += __shfl_xor(v, 8, 64);
            sc[rt][r] = v;
        }

    if (nl == 0) {
#pragma unroll
        for (int rt = 0; rt < 2; ++rt)
#pragma unroll
            for (int r = 0; r < 4; ++r)
                part[wave][rt * 16 + quad * 4 + r] = sc[rt][r];
    }
    __syncthreads();

    if (t < 32) {
        float x = part[0][t] + part[1][t] + part[2][t] + part[3][t];
        if (MASKED) x -= (float)mask[b * Ss + s0 + t] * NEGF;
        out[(size_t)b * Ss + s0 + t] = x;
    }
}

// ---------------- Softmax over S per batch (mask applied) -> att ----------------
__global__ __launch_bounds__(1024) void softmax_kernel(const float* __restrict__ scores,
                                                       const int* __restrict__ mask,
                                                       float* __restrict__ att) {
    int b = blockIdx.x, t = threadIdx.x;
    __shared__ float red[16];
    int idx = b * Ss + t;
    float x = scores[idx] - (float)mask[idx] * NEGF;

    float m = x;
#pragma unroll
    for (int o = 1; o < 64; o <<= 1) m = fmaxf(m, __shfl_xor(m, o, 64));
    if ((t & 63) == 0) red[t >> 6] = m;
    __syncthreads();
    float M = red[0];
#pragma unroll
    for (int j = 1; j < 16; ++j) M = fmaxf(M, red[j]);
    __syncthreads();

    float e = __expf(x - M);
    float s = e;
#pragma unroll
    for (int o = 1; o < 64; o <<= 1) s += __shfl_xor(s, o, 64);
    if ((t & 63) == 0) red[t >> 6] = s;
    __syncthreads();
    float S = 0.f;
#pragma unroll
    for (int j = 0; j < 16; ++j) S += red[j];

    att[idx] = e * __builtin_amdgcn_rcpf(S);
}

// ---------------- Glimpse partial (bf16 ref): gpart[b,q,d] = sum_{s in 1/8th q} att*ref
__global__ __launch_bounds__(256) void glimpse_part(const unsigned* __restrict__ refb,
                                                    const float* __restrict__ att,
                                                    float* __restrict__ gpart) {
    int b = blockIdx.x, q = blockIdx.y, t = threadIdx.x;
    const int c = t & 31;      // 16B chunk: d = c*8 .. c*8+7
    const int rg = t >> 5;     // row group 0..7
    __shared__ float part[8][Hh];
    const unsigned* base = refb + ((size_t)(b * Ss + q * 128)) * (Hh / 2);
    const float* ap = att + b * Ss + q * 128;

    float acc[8] = {0.f, 0.f, 0.f, 0.f, 0.f, 0.f, 0.f, 0.f};
#pragma unroll 4
    for (int it = 0; it < 16; ++it) {
        int row = it * 8 + rg;
        float a = ap[row];
        uint4 v = *(const uint4*)(base + (size_t)row * (Hh / 2) + c * 4);
        acc[0] += a * bflo2f(v.x); acc[1] += a * bfhi2f(v.x);
        acc[2] += a * bflo2f(v.y); acc[3] += a * bfhi2f(v.y);
        acc[4] += a * bflo2f(v.z); acc[5] += a * bfhi2f(v.z);
        acc[6] += a * bflo2f(v.w); acc[7] += a * bfhi2f(v.w);
    }
#pragma unroll
    for (int j = 0; j < 8; ++j) part[rg][c * 8 + j] = acc[j];
    __syncthreads();
    float s = 0.f;
#pragma unroll
    for (int g = 0; g < 8; ++g) s += part[g][t];
    gpart[(size_t)(b * 8 + q) * Hh + t] = s;
}

// ---------------- qbias_p[b,h] = sum_d glimpse[b,d]*wqp[h,d] + bp[h] ------------
__global__ __launch_bounds__(256) void qbias_p_kernel(const float* __restrict__ gpart,
                                                      const float* __restrict__ query,
                                                      const float* __restrict__ wqp,
                                                      const float* __restrict__ bp,
                                                      float* __restrict__ out) {
    int b = blockIdx.x, t = threadIdx.x;
    __shared__ __align__(16) float gl[Hh];
    float g = query[b * Hh + t];
#pragma unroll
    for (int q = 0; q < 8; ++q) g += gpart[(b * 8 + q) * Hh + t];
    gl[t] = g;
    __syncthreads();
    const float4* wr = (const float4*)(wqp + t * Hh);
    const float4* gp = (const float4*)gl;
    float acc = 0.f;
#pragma unroll 8
    for (int i = 0; i < Hh / 4; ++i) {
        float4 w4 = wr[i];
        float4 g4 = gp[i];
        acc += w4.x * g4.x + w4.y * g4.y + w4.z * g4.z + w4.w * g4.w;
    }
    out[b * Hh + t] = acc + bp[t];
}

extern "C" void kernel_launch(void* const* d_in, const int* in_sizes, int n_in,
                              void* d_out, int out_size, void* d_ws, size_t ws_size,
                              hipStream_t stream) {
    const float* ref   = (const float*)d_in[0];
    const float* query = (const float*)d_in[1];
    const int*   mask  = (const int*)d_in[2];
    const float* wg    = (const float*)d_in[3];
    const float* bg    = (const float*)d_in[4];
    const float* wqg   = (const float*)d_in[5];
    const float* vg    = (const float*)d_in[6];
    const float* wp    = (const float*)d_in[7];
    const float* bp    = (const float*)d_in[8];
    const float* wqp   = (const float*)d_in[9];
    const float* vp    = (const float*)d_in[10];
    float* out = (float*)d_out;

    char* ws = (char*)d_ws;
    short* ref_bf   = (short*)(ws + 0);          // 64 MB (B*S*H bf16)
    size_t off = (size_t)Bb * Ss * Hh * 2;
    short* wg_bf    = (short*)(ws + off);               off += 131072;
    short* wp_bf    = (short*)(ws + off);               off += 131072;
    float* qbias_g  = (float*)(ws + off);               off += 131072;
    float* qbias_p  = (float*)(ws + off);               off += 131072;
    float* scores_g = (float*)(ws + off);               off += 524288;
    float* att      = (float*)(ws + off);               off += 524288;
    float* gpart    = (float*)(ws + off);               // 1 MB

    convert_w<<<Hh * Hh / 256, 256, 0, stream>>>(wg, wp, wg_bf, wp_bf);
    dot_qb<<<Bb, Hh, 0, stream>>>(query, wqg, bg, qbias_g);
    // glimpse scores: fp32 ref in, bf16 ref side-output
    scores_v5<0, 1><<<dim3(Bb, Ss / 32), 256, 0, stream>>>(
        ref, nullptr, (unsigned*)ref_bf, wg_bf, qbias_g, vg, nullptr, scores_g);
    softmax_kernel<<<Bb, Ss, 0, stream>>>(scores_g, mask, att);
    glimpse_part<<<dim3(Bb, 8), 256, 0, stream>>>((const unsigned*)ref_bf, att, gpart);
    qbias_p_kernel<<<Bb, Hh, 0, stream>>>(gpart, query, wqp, bp, qbias_p);
    // pointer scores: bf16 ref in, masked, straight to d_out
    scores_v5<1, 0><<<dim3(Bb, Ss / 32), 256, 0, stream>>>(
        nullptr, (const unsigned*)ref_bf, nullptr, wp_bf, qbias_p, vp, mask, out);
}

// Round 6
// 298.343 us; speedup vs baseline: 1.2255x; 1.2255x over previous
//
#include <hip/hip_runtime.h>

// B=128, S=1024, H=256
#define Bb 128
#define Ss 1024
#define Hh 256
#define NEGF 1e9f

typedef short bf16x8 __attribute__((ext_vector_type(8)));
typedef float f32x4 __attribute__((ext_vector_type(4)));

__device__ __forceinline__ short f2bf(float f) {
    union { float f; unsigned u; } c; c.f = f;
    return (short)((c.u + 0x8000u) >> 16);
}

__device__ __forceinline__ float bfhi2f(unsigned u) {
    union { unsigned u; float f; } c; c.u = u & 0xFFFF0000u; return c.f;
}
__device__ __forceinline__ float bflo2f(unsigned u) {
    union { unsigned u; float f; } c; c.u = u << 16; return c.f;
}

__device__ __forceinline__ bf16x8 ld_bf8_f32(const float* p) {
    const float4* p4 = (const float4*)p;
    float4 a = p4[0], b = p4[1];
    bf16x8 r;
    r[0] = f2bf(a.x); r[1] = f2bf(a.y); r[2] = f2bf(a.z); r[3] = f2bf(a.w);
    r[4] = f2bf(b.x); r[5] = f2bf(b.y); r[6] = f2bf(b.z); r[7] = f2bf(b.w);
    return r;
}

__device__ __forceinline__ float fast_tanh(float x) {
    float cl = fminf(fmaxf(x, -10.f), 10.f);
    float e = __expf(2.f * cl);
    return (e - 1.f) * __builtin_amdgcn_rcpf(e + 1.f);
}

// async global->LDS, 16B per lane; dest = (wave-uniform) lds base + lane*16
__device__ __forceinline__ void stage16(const short* g, short* l) {
    __builtin_amdgcn_global_load_lds((const __attribute__((address_space(1))) void*)g,
                                     (__attribute__((address_space(3))) void*)l, 16, 0, 0);
}

// ---------------- prep: convert wg,wp -> bf16 (blocks 0..255); qbias_g (256..383)
__global__ __launch_bounds__(256) void prep_kernel(const float* __restrict__ wg,
                                                   const float* __restrict__ wp,
                                                   const float* __restrict__ query,
                                                   const float* __restrict__ wqg,
                                                   const float* __restrict__ bg,
                                                   short* __restrict__ wgb,
                                                   short* __restrict__ wpb,
                                                   float* __restrict__ qbias_g) {
    int blk = blockIdx.x, t = threadIdx.x;
    if (blk < 256) {
        int i = blk * 256 + t;
        wgb[i] = f2bf(wg[i]);
        wpb[i] = f2bf(wp[i]);
    } else {
        int b = blk - 256;
        const float4* qr = (const float4*)(query + b * Hh);
        const float4* wr = (const float4*)(wqg + t * Hh);
        float acc = 0.f;
#pragma unroll 8
        for (int i = 0; i < Hh / 4; ++i) {
            float4 q4 = qr[i], w4 = wr[i];
            acc += q4.x * w4.x + q4.y * w4.y + q4.z * w4.z + q4.w * w4.w;
        }
        qbias_g[b * Hh + t] = acc + bg[t];
    }
}

// ---------------- Main fused GEMM (r4 structure): grid (B, S/128), 4 waves.
// W double-buffered in LDS via global_load_lds (32 n-rows / 16 KB chunks).
// LOADF32: A-frags converted from fp32 ref, bf16 side-output written from regs.
template <int MASKED, int LOADF32>
__global__ __launch_bounds__(256) void scores_mfma(const float* __restrict__ reff,
                                                   const short* __restrict__ refb_in,
                                                   short* __restrict__ refb_out,
                                                   const short* __restrict__ Wbf,
                                                   const float* __restrict__ qbias,
                                                   const float* __restrict__ vvec,
                                                   const int* __restrict__ mask,
                                                   float* __restrict__ out) {
    __shared__ short Wlds[2][8192];   // 2 x 16 KB (32 n-rows per chunk)
    const int b = blockIdx.x;
    const int s0 = blockIdx.y * 128;
    const int t = threadIdx.x;
    const int wave = t >> 6;
    const int lane = t & 63;
    const int nl = lane & 15;
    const int quad = lane >> 4;
    const int rowbase = s0 + wave * 32;

    // staging source/dest (verified r3/r4 scheme): thread t feeds read-lane (t&63)
    // of LDS line kb=(t>>6) [soff0] and kb=(t>>6)+4 [soff1]
    const int soff0 = (t & 15) * Hh + (t >> 6) * 32 + ((t >> 4) & 3) * 8;  // shorts
    const int soff1 = soff0 + 128;
    const int dbase0 = wave * 512;          // shorts
    const int dbase1 = 2048 + wave * 512;

    // A fragments: A[m][k=kb*32+quad*8+j]
    bf16x8 afrag[2][8];
#pragma unroll
    for (int rt = 0; rt < 2; ++rt) {
        const size_t rowoff = ((size_t)b * Ss + rowbase + rt * 16 + nl) * Hh;
        if (LOADF32) {
            const float* rp = reff + rowoff;
#pragma unroll
            for (int kb = 0; kb < 8; ++kb)
                afrag[rt][kb] = ld_bf8_f32(rp + kb * 32 + quad * 8);
            // side-output: per kb, quads 0-3 write contiguous 64B of the row
            short* dst = refb_out + rowoff;
#pragma unroll
            for (int kb = 0; kb < 8; ++kb)
                *(bf16x8*)(dst + kb * 32 + quad * 8) = afrag[rt][kb];
        } else {
            const short* rp = refb_in + rowoff;
#pragma unroll
            for (int kb = 0; kb < 8; ++kb)
                afrag[rt][kb] = *(const bf16x8*)(rp + kb * 32 + quad * 8);
        }
    }

    // stage chunk 0 (n-rows 0..31)
    stage16(Wbf + soff0, &Wlds[0][dbase0]);
    stage16(Wbf + soff1, &Wlds[0][dbase1]);
    stage16(Wbf + 16 * Hh + soff0, &Wlds[0][4096 + dbase0]);
    stage16(Wbf + 16 * Hh + soff1, &Wlds[0][4096 + dbase1]);
    __syncthreads();

    float sc[2][4] = {{0.f, 0.f, 0.f, 0.f}, {0.f, 0.f, 0.f, 0.f}};

    for (int nc2 = 0; nc2 < 8; ++nc2) {
        const int cur = nc2 & 1;
        if (nc2 < 7) {  // async prefetch next 32-row chunk
            const short* g = Wbf + (size_t)(nc2 + 1) * 32 * Hh;
            stage16(g + soff0, &Wlds[1 - cur][dbase0]);
            stage16(g + soff1, &Wlds[1 - cur][dbase1]);
            stage16(g + 16 * Hh + soff0, &Wlds[1 - cur][4096 + dbase0]);
            stage16(g + 16 * Hh + soff1, &Wlds[1 - cur][4096 + dbase1]);
        }
#pragma unroll
        for (int h = 0; h < 2; ++h) {
            const int n = nc2 * 32 + h * 16 + nl;
            const float qb = qbias[b * Hh + n];
            const float vv = vvec[n];
            bf16x8 bfrag[8];
#pragma unroll
            for (int kb = 0; kb < 8; ++kb)
                bfrag[kb] = *(const bf16x8*)&Wlds[cur][h * 4096 + kb * 512 + lane * 8];
#pragma unroll
            for (int rt = 0; rt < 2; ++rt) {
                f32x4 c = {0.f, 0.f, 0.f, 0.f};
#pragma unroll
                for (int kb = 0; kb < 8; ++kb)
                    c = __builtin_amdgcn_mfma_f32_16x16x32_bf16(afrag[rt][kb], bfrag[kb], c, 0, 0, 0);
                // C/D: col = lane&15 (= n-lane), row = quad*4 + r
#pragma unroll
                for (int r = 0; r < 4; ++r)
                    sc[rt][r] += fast_tanh(c[r] + qb) * vv;
            }
        }
        __syncthreads();  // drains prefetch vmcnt + guards buffer swap
    }

    // reduce over the 16 n-lanes within each quad
#pragma unroll
    for (int rt = 0; rt < 2; ++rt)
#pragma unroll
        for (int r = 0; r < 4; ++r) {
            float v = sc[rt][r];
            v += __shfl_xor(v, 1, 64);
            v += __shfl_xor(v, 2, 64);
            v += __shfl_xor(v, 4, 64);
            v += __shfl_xor(v, 8, 64);
            sc[rt][r] = v;
        }

    if (nl == 0) {
#pragma unroll
        for (int rt = 0; rt < 2; ++rt)
#pragma unroll
            for (int r = 0; r < 4; ++r) {
                int m = rowbase + rt * 16 + quad * 4 + r;
                float v = sc[rt][r];
                if (MASKED) v -= (float)mask[b * Ss + m] * NEGF;
                out[(size_t)b * Ss + m] = v;
            }
    }
}

// ---------------- Softmax over S per batch (mask applied) -> att ----------------
__global__ __launch_bounds__(1024) void softmax_kernel(const float* __restrict__ scores,
                                                       const int* __restrict__ mask,
                                                       float* __restrict__ att) {
    int b = blockIdx.x, t = threadIdx.x;
    __shared__ float red[16];
    int idx = b * Ss + t;
    float x = scores[idx] - (float)mask[idx] * NEGF;

    float m = x;
#pragma unroll
    for (int o = 1; o < 64; o <<= 1) m = fmaxf(m, __shfl_xor(m, o, 64));
    if ((t & 63) == 0) red[t >> 6] = m;
    __syncthreads();
    float M = red[0];
#pragma unroll
    for (int j = 1; j < 16; ++j) M = fmaxf(M, red[j]);
    __syncthreads();

    float e = __expf(x - M);
    float s = e;
#pragma unroll
    for (int o = 1; o < 64; o <<= 1) s += __shfl_xor(s, o, 64);
    if ((t & 63) == 0) red[t >> 6] = s;
    __syncthreads();
    float S = 0.f;
#pragma unroll
    for (int j = 0; j < 16; ++j) S += red[j];

    att[idx] = e * __builtin_amdgcn_rcpf(S);
}

// ---------------- Glimpse partial (bf16 ref): gpart[b,q,d] = sum_{s in 1/8th q} att*ref
__global__ __launch_bounds__(256) void glimpse_part(const unsigned* __restrict__ refb,
                                                    const float* __restrict__ att,
                                                    float* __restrict__ gpart) {
    int b = blockIdx.x, q = blockIdx.y, t = threadIdx.x;
    const int c = t & 31;      // 16B chunk: d = c*8 .. c*8+7
    const int rg = t >> 5;     // row group 0..7
    __shared__ float part[8][Hh];
    const unsigned* base = refb + ((size_t)(b * Ss + q * 128)) * (Hh / 2);
    const float* ap = att + b * Ss + q * 128;

    float acc[8] = {0.f, 0.f, 0.f, 0.f, 0.f, 0.f, 0.f, 0.f};
#pragma unroll 4
    for (int it = 0; it < 16; ++it) {
        int row = it * 8 + rg;
        float a = ap[row];
        uint4 v = *(const uint4*)(base + (size_t)row * (Hh / 2) + c * 4);
        acc[0] += a * bflo2f(v.x); acc[1] += a * bfhi2f(v.x);
        acc[2] += a * bflo2f(v.y); acc[3] += a * bfhi2f(v.y);
        acc[4] += a * bflo2f(v.z); acc[5] += a * bfhi2f(v.z);
        acc[6] += a * bflo2f(v.w); acc[7] += a * bfhi2f(v.w);
    }
#pragma unroll
    for (int j = 0; j < 8; ++j) part[rg][c * 8 + j] = acc[j];
    __syncthreads();
    float s = 0.f;
#pragma unroll
    for (int g = 0; g < 8; ++g) s += part[g][t];
    gpart[(size_t)(b * 8 + q) * Hh + t] = s;
}

// ---------------- qbias_p[b,h] = sum_d glimpse[b,d]*wqp[h,d] + bp[h] ------------
__global__ __launch_bounds__(256) void qbias_p_kernel(const float* __restrict__ gpart,
                                                      const float* __restrict__ query,
                                                      const float* __restrict__ wqp,
                                                      const float* __restrict__ bp,
                                                      float* __restrict__ out) {
    int b = blockIdx.x, t = threadIdx.x;
    __shared__ __align__(16) float gl[Hh];
    float g = query[b * Hh + t];
#pragma unroll
    for (int q = 0; q < 8; ++q) g += gpart[(b * 8 + q) * Hh + t];
    gl[t] = g;
    __syncthreads();
    const float4* wr = (const float4*)(wqp + t * Hh);
    const float4* gp = (const float4*)gl;
    float acc = 0.f;
#pragma unroll 8
    for (int i = 0; i < Hh / 4; ++i) {
        float4 w4 = wr[i];
        float4 g4 = gp[i];
        acc += w4.x * g4.x + w4.y * g4.y + w4.z * g4.z + w4.w * g4.w;
    }
    out[b * Hh + t] = acc + bp[t];
}

extern "C" void kernel_launch(void* const* d_in, const int* in_sizes, int n_in,
                              void* d_out, int out_size, void* d_ws, size_t ws_size,
                              hipStream_t stream) {
    const float* ref   = (const float*)d_in[0];
    const float* query = (const float*)d_in[1];
    const int*   mask  = (const int*)d_in[2];
    const float* wg    = (const float*)d_in[3];
    const float* bg    = (const float*)d_in[4];
    const float* wqg   = (const float*)d_in[5];
    const float* vg    = (const float*)d_in[6];
    const float* wp    = (const float*)d_in[7];
    const float* bp    = (const float*)d_in[8];
    const float* wqp   = (const float*)d_in[9];
    const float* vp    = (const float*)d_in[10];
    float* out = (float*)d_out;

    char* ws = (char*)d_ws;
    short* ref_bf   = (short*)(ws + 0);          // 64 MB (B*S*H bf16)
    size_t off = (size_t)Bb * Ss * Hh * 2;
    short* wg_bf    = (short*)(ws + off);               off += 131072;
    short* wp_bf    = (short*)(ws + off);               off += 131072;
    float* qbias_g  = (float*)(ws + off);               off += 131072;
    float* qbias_p  = (float*)(ws + off);               off += 131072;
    float* scores_g = (float*)(ws + off);               off += 524288;
    float* att      = (float*)(ws + off);               off += 524288;
    float* gpart    = (float*)(ws + off);               // 1 MB

    prep_kernel<<<384, 256, 0, stream>>>(wg, wp, query, wqg, bg, wg_bf, wp_bf, qbias_g);
    // glimpse scores: fp32 ref in, bf16 ref side-output from A-fragment registers
    scores_mfma<0, 1><<<dim3(Bb, Ss / 128), 256, 0, stream>>>(
        ref, nullptr, ref_bf, wg_bf, qbias_g, vg, nullptr, scores_g);
    softmax_kernel<<<Bb, Ss, 0, stream>>>(scores_g, mask, att);
    glimpse_part<<<dim3(Bb, 8), 256, 0, stream>>>((const unsigned*)ref_bf, att, gpart);
    qbias_p_kernel<<<Bb, Hh, 0, stream>>>(gpart, query, wqp, bp, qbias_p);
    // pointer scores: bf16 ref in, masked, straight to d_out
    scores_mfma<1, 0><<<dim3(Bb, Ss / 128), 256, 0, stream>>>(
        nullptr, ref_bf, nullptr, wp_bf, qbias_p, vp, mask, out);
}